// Round 1
// baseline (473.244 us; speedup 1.0000x reference)
//
#include <hip/hip_runtime.h>

// Problem constants
#define B_DIM 2
#define C_DIM 256
#define L_DIM 1536
#define H_DIM 4
#define D_DIM 64
#define RAD   50
#define WIN   101   // 2*RAD+1
#define NLC   786432   // B*C*L

// ---------------------------------------------------------------------------
// Shared GEMM tile body: out[m, n] = sum_k W[m,k] * xb[k, n] + bias[m]
// W is [256 x 256] row-major, xb is [256 x 1536] row-major (one batch slice).
// 64x64 output tile per 256-thread block, K-tile = 32, 4x4 micro-tile.
// ---------------------------------------------------------------------------
__device__ __forceinline__ void gemm_body(const float* __restrict__ xb,
                                          const float* __restrict__ W,
                                          const float* __restrict__ bias,
                                          float* __restrict__ outb)
{
    __shared__ float As[32][68];  // As[k][m] (transposed), padded to kill conflicts
    __shared__ float Bs[32][68];  // Bs[k][n]
    const int tid = threadIdx.x;
    const int tx = tid & 15, ty = tid >> 4;
    const int m0 = blockIdx.y << 6, n0 = blockIdx.x << 6;
    float acc[4][4] = {};
    for (int k0 = 0; k0 < C_DIM; k0 += 32) {
        int f = tid;
        #pragma unroll
        for (int rep = 0; rep < 2; ++rep, f += 256) {
            const int m = f >> 3, c4 = (f & 7) << 2;
            const float4 v = *reinterpret_cast<const float4*>(&W[(m0 + m) * C_DIM + k0 + c4]);
            As[c4 + 0][m] = v.x; As[c4 + 1][m] = v.y;
            As[c4 + 2][m] = v.z; As[c4 + 3][m] = v.w;
        }
        f = tid;
        #pragma unroll
        for (int rep = 0; rep < 2; ++rep, f += 256) {
            const int kk = f >> 4, n4 = (f & 15) << 2;
            *reinterpret_cast<float4*>(&Bs[kk][n4]) =
                *reinterpret_cast<const float4*>(&xb[(k0 + kk) * L_DIM + n0 + n4]);
        }
        __syncthreads();
        #pragma unroll
        for (int kk = 0; kk < 32; ++kk) {
            const float4 a4 = *reinterpret_cast<const float4*>(&As[kk][ty << 2]);
            const float4 b4 = *reinterpret_cast<const float4*>(&Bs[kk][tx << 2]);
            const float a[4]  = {a4.x, a4.y, a4.z, a4.w};
            const float bb[4] = {b4.x, b4.y, b4.z, b4.w};
            #pragma unroll
            for (int i = 0; i < 4; ++i)
                #pragma unroll
                for (int j = 0; j < 4; ++j)
                    acc[i][j] = fmaf(a[i], bb[j], acc[i][j]);
        }
        __syncthreads();
    }
    #pragma unroll
    for (int i = 0; i < 4; ++i) {
        const int m = m0 + (ty << 2) + i;
        const float bv = bias[m];
        float4 o4;
        o4.x = acc[i][0] + bv; o4.y = acc[i][1] + bv;
        o4.z = acc[i][2] + bv; o4.w = acc[i][3] + bv;
        *reinterpret_cast<float4*>(&outb[m * L_DIM + n0 + (tx << 2)]) = o4;
    }
}

// Fused content/query/key conv1x1. grid = (24, 4, 6); z = which*2 + b
__global__ __launch_bounds__(256) void gemm_qkv(
    const float* __restrict__ x,
    const float* __restrict__ Wc, const float* __restrict__ bc,
    const float* __restrict__ Wq, const float* __restrict__ bq,
    const float* __restrict__ Wk, const float* __restrict__ bk,
    float* __restrict__ content, float* __restrict__ q, float* __restrict__ k)
{
    const int z = blockIdx.z;
    const int b = z & 1;
    const int which = z >> 1;
    const float* W    = (which == 0) ? Wc : (which == 1) ? Wq : Wk;
    const float* bias = (which == 0) ? bc : (which == 1) ? bq : bk;
    float* outp       = (which == 0) ? content : (which == 1) ? q : k;
    const int off = b * C_DIM * L_DIM;
    gemm_body(x + off, W, bias, outp + off);
}

// Final conv1x1. grid = (24, 4, 2)
__global__ __launch_bounds__(256) void gemm_f(
    const float* __restrict__ xin, const float* __restrict__ W,
    const float* __restrict__ bias, float* __restrict__ outp)
{
    const int off = blockIdx.z * C_DIM * L_DIM;
    gemm_body(xin + off, W, bias, outp + off);
}

// ---------------------------------------------------------------------------
// Banded attention: one 128-thread block per (b,h,t).
// thread j (0..100) owns band offset j -> s = t - RAD + j, rel-emb row 100-j.
// ---------------------------------------------------------------------------
__global__ __launch_bounds__(128) void attn(
    const float* __restrict__ q, const float* __restrict__ k,
    const float* __restrict__ content, const float* __restrict__ emb,
    float* __restrict__ out)
{
    const int t  = blockIdx.x;
    const int bh = blockIdx.y;
    const float* qb = q       + bh * (D_DIM * L_DIM);
    const float* kb = k       + bh * (D_DIM * L_DIM);
    const float* cb = content + bh * (D_DIM * L_DIM);

    __shared__ float qs[D_DIM];
    __shared__ float wsm[128];
    __shared__ float red[4];

    const int tid = threadIdx.x;
    if (tid < D_DIM) qs[tid] = qb[tid * L_DIM + t];
    __syncthreads();

    // --- dots ---
    float dot = -1e30f;
    const int s = t - RAD + tid;
    if (tid < WIN && s >= 0 && s < L_DIM) {
        float acc = 0.f;
        #pragma unroll 16
        for (int d = 0; d < D_DIM; ++d)
            acc = fmaf(qs[d], kb[d * L_DIM + s], acc);
        float eacc = 0.f;
        const float* er = emb + (100 - tid) * D_DIM;
        #pragma unroll 16
        for (int d = 0; d < D_DIM; ++d)
            eacc = fmaf(qs[d], er[d], eacc);
        dot = acc + 0.3f * eacc;
    }

    // --- softmax over 128 threads (2 waves) ---
    float m = dot;
    #pragma unroll
    for (int off = 1; off < 64; off <<= 1)
        m = fmaxf(m, __shfl_xor(m, off));
    if ((tid & 63) == 0) red[tid >> 6] = m;
    __syncthreads();
    m = fmaxf(red[0], red[1]);
    float w = (dot > -1e29f) ? __expf(dot - m) : 0.f;
    float ssum = w;
    #pragma unroll
    for (int off = 1; off < 64; off <<= 1)
        ssum += __shfl_xor(ssum, off);
    if ((tid & 63) == 0) red[2 + (tid >> 6)] = ssum;
    __syncthreads();
    const float tot = red[2] + red[3];
    w /= tot;
    wsm[tid] = w;   // threads >= WIN wrote w = 0
    __syncthreads();

    // --- output: thread = (half, d); half 0 sums j in [0,51), half 1 [51,101) ---
    const int d    = tid & 63;
    const int half = tid >> 6;
    const int j0 = half ? 51 : 0;
    const int j1 = half ? 101 : 51;
    float acc = 0.f;
    const float* crow = cb + d * L_DIM;
    const float* ecol = emb + d;
    for (int j = j0; j < j1; ++j) {
        const int ss = t - RAD + j;
        if (ss >= 0 && ss < L_DIM) {
            const float wv = wsm[j];
            acc = fmaf(wv, crow[ss] + 0.3f * ecol[(100 - j) * D_DIM], acc);
        }
    }
    __syncthreads();
    wsm[tid] = acc;
    __syncthreads();
    if (tid < 64)
        out[bh * (D_DIM * L_DIM) + tid * L_DIM + t] = wsm[tid] + wsm[tid + 64];
}

// ---------------------------------------------------------------------------
// BatchNorm(train) + ReLU + scale. One block per channel (256 blocks x 256 thr)
// ---------------------------------------------------------------------------
__global__ __launch_bounds__(256) void bn_apply(
    const float* __restrict__ pre, const float* __restrict__ gamma,
    const float* __restrict__ beta, const float* __restrict__ scale,
    float* __restrict__ out)
{
    const int o = blockIdx.x;
    const int tid = threadIdx.x;
    float v[12];
    float sum = 0.f, sumsq = 0.f;
    #pragma unroll
    for (int i = 0; i < 12; ++i) {
        const int b = (i >= 6);
        const int l = (i - 6 * b) * 256 + tid;
        v[i] = pre[(b * C_DIM + o) * L_DIM + l];
        sum += v[i];
        sumsq = fmaf(v[i], v[i], sumsq);
    }
    #pragma unroll
    for (int off = 1; off < 64; off <<= 1) {
        sum   += __shfl_xor(sum, off);
        sumsq += __shfl_xor(sumsq, off);
    }
    __shared__ float rs[4], rq[4];
    const int wave = tid >> 6;
    if ((tid & 63) == 0) { rs[wave] = sum; rq[wave] = sumsq; }
    __syncthreads();
    sum   = rs[0] + rs[1] + rs[2] + rs[3];
    sumsq = rq[0] + rq[1] + rq[2] + rq[3];
    const float mean = sum * (1.f / 3072.f);
    const float var  = sumsq * (1.f / 3072.f) - mean * mean;
    const float inv  = rsqrtf(var + 1e-5f);
    const float g    = gamma[o] * inv;
    const float b2   = beta[o] - mean * g;
    const float sc   = scale[o];
    #pragma unroll
    for (int i = 0; i < 12; ++i) {
        const int b = (i >= 6);
        const int l = (i - 6 * b) * 256 + tid;
        out[(b * C_DIM + o) * L_DIM + l] = fmaxf(fmaf(v[i], g, b2), 0.f) * sc;
    }
}

extern "C" void kernel_launch(void* const* d_in, const int* in_sizes, int n_in,
                              void* d_out, int out_size, void* d_ws, size_t ws_size,
                              hipStream_t stream) {
    const float* x     = (const float*)d_in[0];
    const float* Wc    = (const float*)d_in[1];
    const float* bc    = (const float*)d_in[2];
    const float* Wq    = (const float*)d_in[3];
    const float* bq    = (const float*)d_in[4];
    const float* Wk    = (const float*)d_in[5];
    const float* bk    = (const float*)d_in[6];
    const float* emb   = (const float*)d_in[7];
    const float* Wf    = (const float*)d_in[8];
    const float* bf    = (const float*)d_in[9];
    const float* gamma = (const float*)d_in[10];
    const float* beta  = (const float*)d_in[11];
    const float* scale = (const float*)d_in[12];
    float* out = (float*)d_out;
    float* ws  = (float*)d_ws;

    float* qbuf = ws;             // [B,C,L]
    float* kbuf = ws + NLC;       // [B,C,L]
    float* cbuf = ws + 2 * NLC;   // [B,C,L]
    float* abuf = ws + 3 * NLC;   // [B,C,L] attention output
    float* pbuf = ws + 4 * NLC;   // [B,C,L] pre-BN activations

    dim3 g1(L_DIM / 64, C_DIM / 64, 6);
    gemm_qkv<<<g1, 256, 0, stream>>>(x, Wc, bc, Wq, bq, Wk, bk, cbuf, qbuf, kbuf);

    dim3 g2(L_DIM, B_DIM * H_DIM);
    attn<<<g2, 128, 0, stream>>>(qbuf, kbuf, cbuf, emb, abuf);

    dim3 g3(L_DIM / 64, C_DIM / 64, 2);
    gemm_f<<<g3, 256, 0, stream>>>(abuf, Wf, bf, pbuf);

    bn_apply<<<256, 256, 0, stream>>>(pbuf, gamma, beta, scale, out);
}

// Round 2
// 207.427 us; speedup vs baseline: 2.2815x; 2.2815x over previous
//
#include <hip/hip_runtime.h>

// Problem constants
#define B_DIM 2
#define C_DIM 256
#define L_DIM 1536
#define H_DIM 4
#define D_DIM 64
#define RAD   50
#define WIN   101      // 2*RAD+1
#define NLC   786432   // B*C*L
#define TTILE 64       // t positions per attn block
#define KCOLS 164      // TTILE + 2*RAD
#define KPAD  169      // stride: 169 % 32 = 9, coprime with 32 -> conflict-free
#define QPAD  68
#define WPAD  105

// ---------------------------------------------------------------------------
// Shared GEMM tile body: out[m, n] = sum_k W[m,k] * xb[k, n] + bias[m]
// ---------------------------------------------------------------------------
__device__ __forceinline__ void gemm_body(const float* __restrict__ xb,
                                          const float* __restrict__ W,
                                          const float* __restrict__ bias,
                                          float* __restrict__ outb)
{
    __shared__ float As[32][68];
    __shared__ float Bs[32][68];
    const int tid = threadIdx.x;
    const int tx = tid & 15, ty = tid >> 4;
    const int m0 = blockIdx.y << 6, n0 = blockIdx.x << 6;
    float acc[4][4] = {};
    for (int k0 = 0; k0 < C_DIM; k0 += 32) {
        int f = tid;
        #pragma unroll
        for (int rep = 0; rep < 2; ++rep, f += 256) {
            const int m = f >> 3, c4 = (f & 7) << 2;
            const float4 v = *reinterpret_cast<const float4*>(&W[(m0 + m) * C_DIM + k0 + c4]);
            As[c4 + 0][m] = v.x; As[c4 + 1][m] = v.y;
            As[c4 + 2][m] = v.z; As[c4 + 3][m] = v.w;
        }
        f = tid;
        #pragma unroll
        for (int rep = 0; rep < 2; ++rep, f += 256) {
            const int kk = f >> 4, n4 = (f & 15) << 2;
            *reinterpret_cast<float4*>(&Bs[kk][n4]) =
                *reinterpret_cast<const float4*>(&xb[(k0 + kk) * L_DIM + n0 + n4]);
        }
        __syncthreads();
        #pragma unroll
        for (int kk = 0; kk < 32; ++kk) {
            const float4 a4 = *reinterpret_cast<const float4*>(&As[kk][ty << 2]);
            const float4 b4 = *reinterpret_cast<const float4*>(&Bs[kk][tx << 2]);
            const float a[4]  = {a4.x, a4.y, a4.z, a4.w};
            const float bb[4] = {b4.x, b4.y, b4.z, b4.w};
            #pragma unroll
            for (int i = 0; i < 4; ++i)
                #pragma unroll
                for (int j = 0; j < 4; ++j)
                    acc[i][j] = fmaf(a[i], bb[j], acc[i][j]);
        }
        __syncthreads();
    }
    #pragma unroll
    for (int i = 0; i < 4; ++i) {
        const int m = m0 + (ty << 2) + i;
        const float bv = bias[m];
        float4 o4;
        o4.x = acc[i][0] + bv; o4.y = acc[i][1] + bv;
        o4.z = acc[i][2] + bv; o4.w = acc[i][3] + bv;
        *reinterpret_cast<float4*>(&outb[m * L_DIM + n0 + (tx << 2)]) = o4;
    }
}

__global__ __launch_bounds__(256) void gemm_qkv(
    const float* __restrict__ x,
    const float* __restrict__ Wc, const float* __restrict__ bc,
    const float* __restrict__ Wq, const float* __restrict__ bq,
    const float* __restrict__ Wk, const float* __restrict__ bk,
    float* __restrict__ content, float* __restrict__ q, float* __restrict__ k)
{
    const int z = blockIdx.z;
    const int b = z & 1;
    const int which = z >> 1;
    const float* W    = (which == 0) ? Wc : (which == 1) ? Wq : Wk;
    const float* bias = (which == 0) ? bc : (which == 1) ? bq : bk;
    float* outp       = (which == 0) ? content : (which == 1) ? q : k;
    const int off = b * C_DIM * L_DIM;
    gemm_body(x + off, W, bias, outp + off);
}

__global__ __launch_bounds__(256) void gemm_f(
    const float* __restrict__ xin, const float* __restrict__ W,
    const float* __restrict__ bias, float* __restrict__ outp)
{
    const int off = blockIdx.z * C_DIM * L_DIM;
    gemm_body(xin + off, W, bias, outp + off);
}

// ---------------------------------------------------------------------------
// Banded attention, t-tiled. Block = 256 threads handles (bh, 64 t's).
// Phase 1: dots[t][j] = sum_d q[d][t]*(k[d][s] + 0.3*emb[100-j][d])
// Phase 2: register softmax via 4-lane quad shuffles
// Phase 3: out[d][t]  = sum_j w[t][j]*(c[d][s] + 0.3*emb[100-j][d])
// ---------------------------------------------------------------------------
__global__ __launch_bounds__(256) void attn(
    const float* __restrict__ q, const float* __restrict__ k,
    const float* __restrict__ content, const float* __restrict__ emb,
    float* __restrict__ out)
{
    __shared__ float ks[D_DIM][KPAD];     // k tile, then content tile
    __shared__ float embs[WIN][QPAD];     // embs[row][d]
    __shared__ float qT[D_DIM][QPAD];     // q transposed [tl][d]; reused as out-transpose
    __shared__ float wsm[TTILE][WPAD];    // softmax weights [tl][j]

    const int tid  = threadIdx.x;
    const int t0   = blockIdx.x * TTILE;
    const int bh   = blockIdx.y;
    const int lane = tid & 63;
    const int wv   = tid >> 6;            // wave id 0..3
    const float* qb = q       + bh * (D_DIM * L_DIM);
    const float* kb = k       + bh * (D_DIM * L_DIM);
    const float* cb = content + bh * (D_DIM * L_DIM);
    const int base = t0 - RAD;            // global col of ks col 0

    // ---- stage K, qT, embs ----
    #pragma unroll
    for (int r = 0; r < 16; ++r) {
        const int d = wv * 16 + r;
        for (int c = lane; c < KCOLS; c += 64) {
            const int gc = base + c;
            ks[d][c] = (gc >= 0 && gc < L_DIM) ? kb[d * L_DIM + gc] : 0.f;
        }
        qT[lane][d] = qb[d * L_DIM + t0 + lane];
    }
    for (int idx = tid; idx < WIN * D_DIM; idx += 256)
        embs[idx >> 6][idx & 63] = emb[idx];
    __syncthreads();

    // ---- phase 1: banded dots ----
    const int tl = tid >> 2;              // 0..63
    const int g  = tid & 3;               // quarter of the 101-wide band
    const int jbase = g * 26;
    float acc[26];
    #pragma unroll
    for (int jj = 0; jj < 26; ++jj) acc[jj] = 0.f;
    for (int d = 0; d < D_DIM; ++d) {
        const float qv = qT[tl][d];
        #pragma unroll
        for (int jj = 0; jj < 26; ++jj) {
            const int j = jbase + jj;
            if (j < WIN)
                acc[jj] = fmaf(qv, ks[d][tl + j] + 0.3f * embs[100 - j][d], acc[jj]);
        }
    }
    __syncthreads();   // all ks reads done -> safe to restage

    // ---- restage ks with content (global loads overlap softmax VALU) ----
    #pragma unroll
    for (int r = 0; r < 16; ++r) {
        const int d = wv * 16 + r;
        for (int c = lane; c < KCOLS; c += 64) {
            const int gc = base + c;
            ks[d][c] = (gc >= 0 && gc < L_DIM) ? cb[d * L_DIM + gc] : 0.f;
        }
    }

    // ---- phase 2: softmax in registers, quad reduce ----
    {
        const int t = t0 + tl;
        #pragma unroll
        for (int jj = 0; jj < 26; ++jj) {
            const int j = jbase + jj;
            const int s = t - RAD + j;
            if (j >= WIN || s < 0 || s >= L_DIM) acc[jj] = -1e30f;
        }
        float m = -1e30f;
        #pragma unroll
        for (int jj = 0; jj < 26; ++jj) m = fmaxf(m, acc[jj]);
        m = fmaxf(m, __shfl_xor(m, 1));
        m = fmaxf(m, __shfl_xor(m, 2));
        float ssum = 0.f;
        #pragma unroll
        for (int jj = 0; jj < 26; ++jj) { acc[jj] = __expf(acc[jj] - m); ssum += acc[jj]; }
        ssum += __shfl_xor(ssum, 1);
        ssum += __shfl_xor(ssum, 2);
        const float inv = 1.f / ssum;
        #pragma unroll
        for (int jj = 0; jj < 26; ++jj)
            wsm[tl][jbase + jj] = acc[jj] * inv;   // cols 101..103 land in pad
    }
    __syncthreads();   // wsm written + content staged

    // ---- phase 3: banded PV (+emb) ----
    const int d3 = lane;
    float oacc[16];
    #pragma unroll
    for (int tt = 0; tt < 16; ++tt) oacc[tt] = 0.f;
    for (int j = 0; j < WIN; ++j) {
        const float ev = 0.3f * embs[100 - j][d3];
        #pragma unroll
        for (int tt = 0; tt < 16; ++tt) {
            const int tle = (wv << 4) + tt;
            oacc[tt] = fmaf(wsm[tle][j], ks[d3][tle + j] + ev, oacc[tt]);
        }
    }

    // ---- transpose through qT (free: qT reads done in phase 1) ----
    #pragma unroll
    for (int tt = 0; tt < 16; ++tt)
        qT[d3][(wv << 4) + tt] = oacc[tt];
    __syncthreads();
    float* ob = out + bh * (D_DIM * L_DIM);
    #pragma unroll
    for (int r = 0; r < 16; ++r) {
        const int d = wv * 16 + r;
        ob[d * L_DIM + t0 + lane] = qT[d][lane];
    }
}

// ---------------------------------------------------------------------------
// BatchNorm(train) + ReLU + scale
// ---------------------------------------------------------------------------
__global__ __launch_bounds__(256) void bn_apply(
    const float* __restrict__ pre, const float* __restrict__ gamma,
    const float* __restrict__ beta, const float* __restrict__ scale,
    float* __restrict__ out)
{
    const int o = blockIdx.x;
    const int tid = threadIdx.x;
    float v[12];
    float sum = 0.f, sumsq = 0.f;
    #pragma unroll
    for (int i = 0; i < 12; ++i) {
        const int b = (i >= 6);
        const int l = (i - 6 * b) * 256 + tid;
        v[i] = pre[(b * C_DIM + o) * L_DIM + l];
        sum += v[i];
        sumsq = fmaf(v[i], v[i], sumsq);
    }
    #pragma unroll
    for (int off = 1; off < 64; off <<= 1) {
        sum   += __shfl_xor(sum, off);
        sumsq += __shfl_xor(sumsq, off);
    }
    __shared__ float rs[4], rq[4];
    const int wave = tid >> 6;
    if ((tid & 63) == 0) { rs[wave] = sum; rq[wave] = sumsq; }
    __syncthreads();
    sum   = rs[0] + rs[1] + rs[2] + rs[3];
    sumsq = rq[0] + rq[1] + rq[2] + rq[3];
    const float mean = sum * (1.f / 3072.f);
    const float var  = sumsq * (1.f / 3072.f) - mean * mean;
    const float inv  = rsqrtf(var + 1e-5f);
    const float gm   = gamma[o] * inv;
    const float b2   = beta[o] - mean * gm;
    const float sc   = scale[o];
    #pragma unroll
    for (int i = 0; i < 12; ++i) {
        const int b = (i >= 6);
        const int l = (i - 6 * b) * 256 + tid;
        out[(b * C_DIM + o) * L_DIM + l] = fmaxf(fmaf(v[i], gm, b2), 0.f) * sc;
    }
}

extern "C" void kernel_launch(void* const* d_in, const int* in_sizes, int n_in,
                              void* d_out, int out_size, void* d_ws, size_t ws_size,
                              hipStream_t stream) {
    const float* x     = (const float*)d_in[0];
    const float* Wc    = (const float*)d_in[1];
    const float* bc    = (const float*)d_in[2];
    const float* Wq    = (const float*)d_in[3];
    const float* bq    = (const float*)d_in[4];
    const float* Wk    = (const float*)d_in[5];
    const float* bk    = (const float*)d_in[6];
    const float* emb   = (const float*)d_in[7];
    const float* Wf    = (const float*)d_in[8];
    const float* bf    = (const float*)d_in[9];
    const float* gamma = (const float*)d_in[10];
    const float* beta  = (const float*)d_in[11];
    const float* scale = (const float*)d_in[12];
    float* out = (float*)d_out;
    float* ws  = (float*)d_ws;

    float* qbuf = ws;             // [B,C,L]
    float* kbuf = ws + NLC;       // [B,C,L]
    float* cbuf = ws + 2 * NLC;   // [B,C,L]
    float* abuf = ws + 3 * NLC;   // [B,C,L] attention output
    float* pbuf = ws + 4 * NLC;   // [B,C,L] pre-BN activations

    dim3 g1(L_DIM / 64, C_DIM / 64, 6);
    gemm_qkv<<<g1, 256, 0, stream>>>(x, Wc, bc, Wq, bq, Wk, bk, cbuf, qbuf, kbuf);

    dim3 g2(L_DIM / TTILE, B_DIM * H_DIM);
    attn<<<g2, 256, 0, stream>>>(qbuf, kbuf, cbuf, emb, abuf);

    dim3 g3(L_DIM / 64, C_DIM / 64, 2);
    gemm_f<<<g3, 256, 0, stream>>>(abuf, Wf, bf, pbuf);

    bn_apply<<<256, 256, 0, stream>>>(pbuf, gamma, beta, scale, out);
}

// Round 4
// 204.909 us; speedup vs baseline: 2.3095x; 1.0123x over previous
//
#include <hip/hip_runtime.h>

// Problem constants
#define B_DIM 2
#define C_DIM 256
#define L_DIM 1536
#define H_DIM 4
#define D_DIM 64
#define RAD   50
#define WIN   101      // 2*RAD+1
#define NLC   786432   // B*C*L
#define CL    393216   // C*L

// attn tiling
#define TT32  32       // t positions per attn block
#define KC2   132      // TT32 + 2*RAD
#define KP2   137      // 137%32=9, coprime -> conflict-free column reads
#define QP2   69       // 69%32=5, coprime
#define WP2   105
#define EP2   33
#define JROWS 104      // padded band width (8*13)

// ---------------------------------------------------------------------------
// GEMM tile body: out[m,n] = sum_{k in [k0s,k0e)} W[m,k]*xb[k,n] (+bias[m])
// ---------------------------------------------------------------------------
__device__ __forceinline__ void gemm_body(const float* __restrict__ xb,
                                          const float* __restrict__ W,
                                          const float* __restrict__ bias,
                                          float* __restrict__ outb,
                                          int k0s, int k0e)
{
    __shared__ float As[32][68];
    __shared__ float Bs[32][68];
    const int tid = threadIdx.x;
    const int tx = tid & 15, ty = tid >> 4;
    const int m0 = blockIdx.y << 6, n0 = blockIdx.x << 6;
    float acc[4][4] = {};
    for (int k0 = k0s; k0 < k0e; k0 += 32) {
        int f = tid;
        #pragma unroll
        for (int rep = 0; rep < 2; ++rep, f += 256) {
            const int m = f >> 3, c4 = (f & 7) << 2;
            const float4 v = *reinterpret_cast<const float4*>(&W[(m0 + m) * C_DIM + k0 + c4]);
            As[c4 + 0][m] = v.x; As[c4 + 1][m] = v.y;
            As[c4 + 2][m] = v.z; As[c4 + 3][m] = v.w;
        }
        f = tid;
        #pragma unroll
        for (int rep = 0; rep < 2; ++rep, f += 256) {
            const int kk = f >> 4, n4 = (f & 15) << 2;
            *reinterpret_cast<float4*>(&Bs[kk][n4]) =
                *reinterpret_cast<const float4*>(&xb[(k0 + kk) * L_DIM + n0 + n4]);
        }
        __syncthreads();
        #pragma unroll
        for (int kk = 0; kk < 32; ++kk) {
            const float4 a4 = *reinterpret_cast<const float4*>(&As[kk][ty << 2]);
            const float4 b4 = *reinterpret_cast<const float4*>(&Bs[kk][tx << 2]);
            const float a[4]  = {a4.x, a4.y, a4.z, a4.w};
            const float bb[4] = {b4.x, b4.y, b4.z, b4.w};
            #pragma unroll
            for (int i = 0; i < 4; ++i)
                #pragma unroll
                for (int j = 0; j < 4; ++j)
                    acc[i][j] = fmaf(a[i], bb[j], acc[i][j]);
        }
        __syncthreads();
    }
    #pragma unroll
    for (int i = 0; i < 4; ++i) {
        const int m = m0 + (ty << 2) + i;
        const float bv = bias ? bias[m] : 0.f;
        float4 o4;
        o4.x = acc[i][0] + bv; o4.y = acc[i][1] + bv;
        o4.z = acc[i][2] + bv; o4.w = acc[i][3] + bv;
        *reinterpret_cast<float4*>(&outb[m * L_DIM + n0 + (tx << 2)]) = o4;
    }
}

// Fused content/query/key conv1x1. grid = (24, 4, 6); z = which*2 + b
__global__ __launch_bounds__(256) void gemm_qkv(
    const float* __restrict__ x,
    const float* __restrict__ Wc, const float* __restrict__ bc,
    const float* __restrict__ Wq, const float* __restrict__ bq,
    const float* __restrict__ Wk, const float* __restrict__ bk,
    float* __restrict__ content, float* __restrict__ q, float* __restrict__ k)
{
    const int z = blockIdx.z;
    const int b = z & 1;
    const int which = z >> 1;
    const float* W    = (which == 0) ? Wc : (which == 1) ? Wq : Wk;
    const float* bias = (which == 0) ? bc : (which == 1) ? bq : bk;
    float* outp       = (which == 0) ? content : (which == 1) ? q : k;
    const int off = b * CL;
    gemm_body(x + off, W, bias, outp + off, 0, C_DIM);
}

// Final conv1x1, split-K. grid = (24, 4, 4); z: b = z&1, khalf = z>>1
__global__ __launch_bounds__(256) void gemm_f(
    const float* __restrict__ xin, const float* __restrict__ W,
    const float* __restrict__ bias,
    float* __restrict__ p0, float* __restrict__ p1)
{
    const int z = blockIdx.z;
    const int b = z & 1;
    const int kh = z >> 1;
    float* outp = (kh == 0) ? p0 : p1;
    gemm_body(xin + b * CL, W, kh == 0 ? bias : nullptr, outp + b * CL,
              kh * 128, kh * 128 + 128);
}

// ---------------------------------------------------------------------------
// edot[bh][j][t] = 0.3 * sum_d q[bh,d,t] * emb[100-j][d]   (j in [0,104))
// grid = (24, 8), 256 threads. Heavy B-reuse GEMM.
// ---------------------------------------------------------------------------
__global__ __launch_bounds__(256) void edot_kernel(
    const float* __restrict__ q, const float* __restrict__ emb,
    float* __restrict__ edot)
{
    __shared__ float qT64[64][QP2];   // [t][d]
    __shared__ float Eb[64][WP2];     // [d][j] = 0.3*emb[100-j][d]
    const int tid = threadIdx.x;
    const int t0 = blockIdx.x * 64;
    const int bh = blockIdx.y;
    const float* qb = q + bh * (D_DIM * L_DIM);

    for (int idx = tid; idx < 64 * 64; idx += 256) {
        const int t = idx & 63, d = idx >> 6;
        qT64[t][d] = qb[d * L_DIM + t0 + t];
    }
    for (int idx = tid; idx < 64 * JROWS; idx += 256) {
        const int d = idx & 63, j = idx >> 6;
        Eb[d][j] = (j < WIN) ? 0.3f * emb[(100 - j) * D_DIM + d] : 0.f;
    }
    __syncthreads();

    const int tt = tid & 31;
    const int jg = tid >> 5;          // 0..7, owns 13 j's
    float acc0[13] = {}, acc1[13] = {};
    for (int d = 0; d < 64; ++d) {
        const float q0 = qT64[tt][d];
        const float q1 = qT64[tt + 32][d];
        #pragma unroll
        for (int i = 0; i < 13; ++i) {
            const float e = Eb[d][jg * 13 + i];
            acc0[i] = fmaf(q0, e, acc0[i]);
            acc1[i] = fmaf(q1, e, acc1[i]);
        }
    }
    float* eb = edot + (size_t)bh * JROWS * L_DIM + t0;
    #pragma unroll
    for (int i = 0; i < 13; ++i) {
        const int j = jg * 13 + i;
        eb[j * L_DIM + tt]      = acc0[i];
        eb[j * L_DIM + tt + 32] = acc1[i];
    }
}

// ---------------------------------------------------------------------------
// Banded attention core. Block = 256 thr, (bh, 32 t's). grid = (48, 8).
// ---------------------------------------------------------------------------
__global__ __launch_bounds__(256) void attn(
    const float* __restrict__ q, const float* __restrict__ k,
    const float* __restrict__ content, const float* __restrict__ emb,
    const float* __restrict__ edot, float* __restrict__ out)
{
    __shared__ float ks[D_DIM][KP2];   // k tile, then content tile
    __shared__ float qT[TT32][QP2];    // [t][d]; reused for output transpose
    __shared__ float eds[JROWS][EP2];  // edot tile [j][t]
    __shared__ float wsm[TT32][WP2];   // softmax weights [t][j]

    const int tid  = threadIdx.x;
    const int t0   = blockIdx.x * TT32;
    const int bh   = blockIdx.y;
    const int lane = tid & 63;
    const int wv   = tid >> 6;
    const float* qb = q       + bh * (D_DIM * L_DIM);
    const float* kb = k       + bh * (D_DIM * L_DIM);
    const float* cb = content + bh * (D_DIM * L_DIM);
    const int base = t0 - RAD;

    // ---- stage K tile, qT, edot tile ----
    for (int d = wv; d < D_DIM; d += 4)
        for (int c = lane; c < KC2; c += 64) {
            const int gc = base + c;
            ks[d][c] = (gc >= 0 && gc < L_DIM) ? kb[d * L_DIM + gc] : 0.f;
        }
    for (int idx = tid; idx < D_DIM * TT32; idx += 256) {
        const int t = idx & 31, d = idx >> 5;
        qT[t][d] = qb[d * L_DIM + t0 + t];
    }
    for (int idx = tid; idx < JROWS * TT32; idx += 256) {
        const int t = idx & 31, j = idx >> 5;
        eds[j][t] = edot[((size_t)bh * JROWS + j) * L_DIM + t0 + t];
    }
    __syncthreads();

    // ---- phase 1: banded dots ----
    const int tl = tid >> 3;          // 0..31 (t within tile)
    const int jg = tid & 7;           // octet: 13 j's each
    const int jb = jg * 13;
    float acc[13];
    #pragma unroll
    for (int i = 0; i < 13; ++i) acc[i] = 0.f;
    for (int d = 0; d < D_DIM; ++d) {
        const float qv = qT[tl][d];
        #pragma unroll
        for (int i = 0; i < 13; ++i)
            acc[i] = fmaf(qv, ks[d][tl + jb + i], acc[i]);
    }
    #pragma unroll
    for (int i = 0; i < 13; ++i) acc[i] += eds[jb + i][tl];  // 0.3 folded in
    __syncthreads();   // ks reads done -> safe to restage

    // ---- restage ks with content ----
    for (int d = wv; d < D_DIM; d += 4)
        for (int c = lane; c < KC2; c += 64) {
            const int gc = base + c;
            ks[d][c] = (gc >= 0 && gc < L_DIM) ? cb[d * L_DIM + gc] : 0.f;
        }

    // ---- phase 2: softmax (8-lane octet reduce) ----
    {
        const int t = t0 + tl;
        #pragma unroll
        for (int i = 0; i < 13; ++i) {
            const int j = jb + i;
            const int s = t - RAD + j;
            if (j >= WIN || s < 0 || s >= L_DIM) acc[i] = -1e30f;
        }
        float m = acc[0];
        #pragma unroll
        for (int i = 1; i < 13; ++i) m = fmaxf(m, acc[i]);
        m = fmaxf(m, __shfl_xor(m, 1));
        m = fmaxf(m, __shfl_xor(m, 2));
        m = fmaxf(m, __shfl_xor(m, 4));
        float ssum = 0.f;
        #pragma unroll
        for (int i = 0; i < 13; ++i) { acc[i] = __expf(acc[i] - m); ssum += acc[i]; }
        ssum += __shfl_xor(ssum, 1);
        ssum += __shfl_xor(ssum, 2);
        ssum += __shfl_xor(ssum, 4);
        const float inv = 1.f / ssum;
        #pragma unroll
        for (int i = 0; i < 13; ++i) wsm[tl][jb + i] = acc[i] * inv;
    }
    __syncthreads();   // wsm ready + content staged

    // ---- phase 3: banded PV + emb term (emb from global, L1-resident) ----
    const int d3 = lane;
    float oacc[8];
    #pragma unroll
    for (int tt = 0; tt < 8; ++tt) oacc[tt] = 0.f;
    const float* ecol = emb + d3;
    for (int j = 0; j < WIN; ++j) {
        const float ev = 0.3f * ecol[(100 - j) * D_DIM];
        #pragma unroll
        for (int tt = 0; tt < 8; ++tt) {
            const int tle = (wv << 3) + tt;
            oacc[tt] = fmaf(wsm[tle][j], ks[d3][tle + j] + ev, oacc[tt]);
        }
    }
    __syncthreads();
    #pragma unroll
    for (int tt = 0; tt < 8; ++tt)
        qT[(wv << 3) + tt][d3] = oacc[tt];
    __syncthreads();
    float* ob = out + bh * (D_DIM * L_DIM);
    {
        const int t  = tid & 31;
        const int dg = tid >> 5;   // 0..7
        #pragma unroll
        for (int di = 0; di < 8; ++di) {
            const int d = (dg << 3) + di;
            ob[d * L_DIM + t0 + t] = qT[t][d];
        }
    }
}

// ---------------------------------------------------------------------------
// BatchNorm(train) + ReLU + scale; sums the two split-K partials.
// ---------------------------------------------------------------------------
__global__ __launch_bounds__(256) void bn_apply(
    const float* __restrict__ p0, const float* __restrict__ p1,
    const float* __restrict__ gamma, const float* __restrict__ beta,
    const float* __restrict__ scale, float* __restrict__ out)
{
    const int o = blockIdx.x;
    const int tid = threadIdx.x;
    float v[12];
    float sum = 0.f, sumsq = 0.f;
    #pragma unroll
    for (int i = 0; i < 12; ++i) {
        const int b = (i >= 6);
        const int l = (i - 6 * b) * 256 + tid;
        const int idx = (b * C_DIM + o) * L_DIM + l;
        v[i] = p0[idx] + p1[idx];
        sum += v[i];
        sumsq = fmaf(v[i], v[i], sumsq);
    }
    #pragma unroll
    for (int off = 1; off < 64; off <<= 1) {
        sum   += __shfl_xor(sum, off);
        sumsq += __shfl_xor(sumsq, off);
    }
    __shared__ float rs[4], rq[4];
    const int wave = tid >> 6;
    if ((tid & 63) == 0) { rs[wave] = sum; rq[wave] = sumsq; }
    __syncthreads();
    sum   = rs[0] + rs[1] + rs[2] + rs[3];
    sumsq = rq[0] + rq[1] + rq[2] + rq[3];
    const float mean = sum * (1.f / 3072.f);
    const float var  = sumsq * (1.f / 3072.f) - mean * mean;
    const float inv  = rsqrtf(var + 1e-5f);
    const float gm   = gamma[o] * inv;
    const float b2   = beta[o] - mean * gm;
    const float sc   = scale[o];
    #pragma unroll
    for (int i = 0; i < 12; ++i) {
        const int b = (i >= 6);
        const int l = (i - 6 * b) * 256 + tid;
        out[(b * C_DIM + o) * L_DIM + l] = fmaxf(fmaf(v[i], gm, b2), 0.f) * sc;
    }
}

extern "C" void kernel_launch(void* const* d_in, const int* in_sizes, int n_in,
                              void* d_out, int out_size, void* d_ws, size_t ws_size,
                              hipStream_t stream) {
    const float* x     = (const float*)d_in[0];
    const float* Wc    = (const float*)d_in[1];
    const float* bc    = (const float*)d_in[2];
    const float* Wq    = (const float*)d_in[3];
    const float* bq    = (const float*)d_in[4];
    const float* Wk    = (const float*)d_in[5];
    const float* bk    = (const float*)d_in[6];
    const float* emb   = (const float*)d_in[7];
    const float* Wf    = (const float*)d_in[8];
    const float* bf    = (const float*)d_in[9];
    const float* gamma = (const float*)d_in[10];
    const float* beta  = (const float*)d_in[11];
    const float* scale = (const float*)d_in[12];
    float* out = (float*)d_out;
    float* ws  = (float*)d_ws;

    float* qbuf  = ws;                       // [B,C,L]
    float* kbuf  = ws + NLC;                 // [B,C,L]
    float* cbuf  = ws + 2 * NLC;             // [B,C,L]
    float* abuf  = ws + 3 * NLC;             // [B,C,L] attention output
    float* ebuf  = ws + 4 * NLC;             // [BH, 104, L] edot
    float* pbuf0 = ebuf + 8 * JROWS * L_DIM; // [B,C,L] split-K partial 0
    float* pbuf1 = pbuf0 + NLC;              // [B,C,L] split-K partial 1

    dim3 g1(L_DIM / 64, C_DIM / 64, 6);
    gemm_qkv<<<g1, 256, 0, stream>>>(x, Wc, bc, Wq, bq, Wk, bk, cbuf, qbuf, kbuf);

    dim3 ge(L_DIM / 64, B_DIM * H_DIM);
    edot_kernel<<<ge, 256, 0, stream>>>(qbuf, emb, ebuf);

    dim3 g2(L_DIM / TT32, B_DIM * H_DIM);
    attn<<<g2, 256, 0, stream>>>(qbuf, kbuf, cbuf, emb, ebuf, abuf);

    dim3 g3(L_DIM / 64, C_DIM / 64, 4);
    gemm_f<<<g3, 256, 0, stream>>>(abuf, Wf, bf, pbuf0, pbuf1);

    bn_apply<<<256, 256, 0, stream>>>(pbuf0, pbuf1, gamma, beta, scale, out);
}

// Round 7
// 124.653 us; speedup vs baseline: 3.7965x; 1.6438x over previous
//
#include <hip/hip_runtime.h>

typedef unsigned short u16;
typedef unsigned int u32;
typedef __bf16 bf16x8 __attribute__((ext_vector_type(8)));
typedef float f32x4 __attribute__((ext_vector_type(4)));

#define MFMA16 __builtin_amdgcn_mfma_f32_16x16x32_bf16

__device__ __forceinline__ u16 f2bf(float f) {
    u32 u = __float_as_uint(f);
    u32 r = (u + 0x7fffu + ((u >> 16) & 1u)) >> 16;
    return (u16)r;
}
__device__ __forceinline__ float bf2f(u16 h) {
    return __uint_as_float(((u32)h) << 16);
}
__device__ __forceinline__ bf16x8 ld8(const u16* p) {
    return *reinterpret_cast<const bf16x8*>(p);
}

// ---------------------------------------------------------------------------
// prep_x: x [b][c][l] fp32 -> xT [b][l][c] bf16.  grid (24, 4, 2), 256 thr
// ---------------------------------------------------------------------------
__global__ __launch_bounds__(256) void prep_x(const float* __restrict__ x,
                                              u16* __restrict__ xT)
{
    __shared__ u16 tile[64][65];
    const int tid = threadIdx.x;
    const int b = blockIdx.z, c0 = blockIdx.y * 64, l0 = blockIdx.x * 64;
    const int cc = tid >> 2, lq = (tid & 3) * 16;
    const float* xp = x + (size_t)((b * 256 + c0 + cc) * 1536 + l0 + lq);
    #pragma unroll
    for (int i = 0; i < 4; ++i) {
        float4 v = *reinterpret_cast<const float4*>(xp + i * 4);
        tile[cc][lq + i * 4 + 0] = f2bf(v.x);
        tile[cc][lq + i * 4 + 1] = f2bf(v.y);
        tile[cc][lq + i * 4 + 2] = f2bf(v.z);
        tile[cc][lq + i * 4 + 3] = f2bf(v.w);
    }
    __syncthreads();
    const int ll = tid >> 2, cq = (tid & 3) * 16;
    u16* op = xT + (size_t)((b * 1536 + l0 + ll) * 256 + c0 + cq);
    #pragma unroll
    for (int i = 0; i < 16; ++i) op[i] = tile[cq + i][ll];
}

// ---------------------------------------------------------------------------
// prep_we: W's fp32->bf16; embR[112][64] = 0.3*emb[100-j][d]; embT[64][128] same^T
// grid 256 x 256
// ---------------------------------------------------------------------------
__global__ __launch_bounds__(256) void prep_we(
    const float* __restrict__ Wc, const float* __restrict__ Wq,
    const float* __restrict__ Wk, const float* __restrict__ Wf,
    const float* __restrict__ emb,
    u16* __restrict__ wcb, u16* __restrict__ wqb, u16* __restrict__ wkb,
    u16* __restrict__ wfb, u16* __restrict__ embR, u16* __restrict__ embT)
{
    const int i = blockIdx.x * 256 + threadIdx.x;
    if (i < 65536) {
        wcb[i] = f2bf(Wc[i]); wqb[i] = f2bf(Wq[i]);
        wkb[i] = f2bf(Wk[i]); wfb[i] = f2bf(Wf[i]);
    }
    if (i < 112 * 64) {
        int j = i >> 6, d = i & 63;
        embR[i] = (j < 101) ? f2bf(0.3f * emb[(100 - j) * 64 + d]) : (u16)0;
    }
    if (i < 64 * 128) {
        int d = i >> 7, j = i & 127;
        embT[i] = (j < 101) ? f2bf(0.3f * emb[(100 - j) * 64 + d]) : (u16)0;
    }
}

// ---------------------------------------------------------------------------
// gemm_qk: q/k [b][l][ch] bf16 = xT[l][:] . W[ch][:] + bias[ch]
// grid (24, 4, 4): z = which*2 + b.  256 thr = 4 waves (2 l-sub x 2 ch-sub)
// ---------------------------------------------------------------------------
__global__ __launch_bounds__(256) void gemm_qk(
    const u16* __restrict__ xT,
    const u16* __restrict__ Wq, const float* __restrict__ bq,
    const u16* __restrict__ Wk, const float* __restrict__ bk,
    u16* __restrict__ qo, u16* __restrict__ ko)
{
    const int tid = threadIdx.x, wv = tid >> 6, lane = tid & 63;
    const int l15 = lane & 15, kg8 = (lane >> 4) * 8;
    const int z = blockIdx.z, b = z & 1, which = z >> 1;
    const u16* W = which ? Wk : Wq;
    const float* bias = which ? bk : bq;
    u16* outp = which ? ko : qo;
    const int m0 = blockIdx.x * 64 + (wv & 1) * 32;
    const int ch0 = blockIdx.y * 64 + (wv >> 1) * 32;
    const u16* ap = xT + (size_t)(b * 1536 + m0 + l15) * 256 + kg8;
    const u16* bp = W + (size_t)(ch0 + l15) * 256 + kg8;
    const f32x4 zf = {0.f, 0.f, 0.f, 0.f};
    f32x4 acc[2][2] = {{zf, zf}, {zf, zf}};
    #pragma unroll
    for (int kd = 0; kd < 8; ++kd) {
        bf16x8 a0 = ld8(ap + kd * 32);
        bf16x8 a1 = ld8(ap + 4096 + kd * 32);
        bf16x8 b0 = ld8(bp + kd * 32);
        bf16x8 b1 = ld8(bp + 4096 + kd * 32);
        acc[0][0] = MFMA16(a0, b0, acc[0][0], 0, 0, 0);
        acc[0][1] = MFMA16(a0, b1, acc[0][1], 0, 0, 0);
        acc[1][0] = MFMA16(a1, b0, acc[1][0], 0, 0, 0);
        acc[1][1] = MFMA16(a1, b1, acc[1][1], 0, 0, 0);
    }
    float bv[2];
    bv[0] = bias[ch0 + l15];
    bv[1] = bias[ch0 + 16 + l15];
    #pragma unroll
    for (int mf = 0; mf < 2; ++mf)
        #pragma unroll
        for (int nf = 0; nf < 2; ++nf)
            #pragma unroll
            for (int r = 0; r < 4; ++r) {
                const int row = m0 + mf * 16 + (lane >> 4) * 4 + r;
                outp[(size_t)(b * 1536 + row) * 256 + ch0 + nf * 16 + l15] =
                    f2bf(acc[mf][nf][r] + bv[nf]);
            }
}

// ---------------------------------------------------------------------------
// gemm_cf: out [b][ch][l] bf16 = W[ch][:] . srcT[l][:] + bias[ch]
// srcT is [b][l][256] bf16 (xT or attn output). grid (24, 4, 2): z = b
// ---------------------------------------------------------------------------
__global__ __launch_bounds__(256) void gemm_cf(
    const u16* __restrict__ W, const float* __restrict__ bias,
    const u16* __restrict__ srcT, u16* __restrict__ outp)
{
    const int tid = threadIdx.x, wv = tid >> 6, lane = tid & 63;
    const int l15 = lane & 15, kg8 = (lane >> 4) * 8;
    const int b = blockIdx.z;
    const int l0 = blockIdx.x * 64 + (wv & 1) * 32;
    const int ch0 = blockIdx.y * 64 + (wv >> 1) * 32;
    const u16* ap = W + (size_t)(ch0 + l15) * 256 + kg8;
    const u16* bp = srcT + (size_t)(b * 1536 + l0 + l15) * 256 + kg8;
    const f32x4 zf = {0.f, 0.f, 0.f, 0.f};
    f32x4 acc[2][2] = {{zf, zf}, {zf, zf}};
    #pragma unroll
    for (int kd = 0; kd < 8; ++kd) {
        bf16x8 a0 = ld8(ap + kd * 32);
        bf16x8 a1 = ld8(ap + 4096 + kd * 32);
        bf16x8 b0 = ld8(bp + kd * 32);
        bf16x8 b1 = ld8(bp + 4096 + kd * 32);
        acc[0][0] = MFMA16(a0, b0, acc[0][0], 0, 0, 0);
        acc[0][1] = MFMA16(a0, b1, acc[0][1], 0, 0, 0);
        acc[1][0] = MFMA16(a1, b0, acc[1][0], 0, 0, 0);
        acc[1][1] = MFMA16(a1, b1, acc[1][1], 0, 0, 0);
    }
    #pragma unroll
    for (int mf = 0; mf < 2; ++mf)
        #pragma unroll
        for (int r = 0; r < 4; ++r) {
            const int ch = ch0 + mf * 16 + (lane >> 4) * 4 + r;
            const float bv = bias[ch];
            #pragma unroll
            for (int nf = 0; nf < 2; ++nf)
                outp[(size_t)(b * 256 + ch) * 1536 + l0 + nf * 16 + l15] =
                    f2bf(acc[mf][nf][r] + bv);
        }
}

// ---------------------------------------------------------------------------
// attn_mfma: per-wave 16-t tile of banded attention, all MFMA.
// q,k: [b][l][ch] bf16; cont: [b][ch][l] bf16; out: [b][l][ch] bf16.
// Window: cs in [0,144), s = tt0 - 64 + cs; band j = cs - t - 14 in [0,101).
// grid (48, 8), 128 thr = 2 waves.
// ---------------------------------------------------------------------------
#define WST 168   // w_lds stride (shorts): 336B = 16B*21, banks 336/4%32=20
#define WBST 136  // wband stride: 272B = 16B*17, banks 4
#define BST 114   // band-scratch stride

__global__ __launch_bounds__(128) void attn_mfma(
    const u16* __restrict__ q, const u16* __restrict__ k,
    const u16* __restrict__ cont, const u16* __restrict__ embR,
    const u16* __restrict__ embT, u16* __restrict__ outp)
{
    __shared__ u16 wls[2][16][WST];
    __shared__ u16 wbs[2][16][WBST];
    __shared__ u16 bss[2][16][BST];
    const int tid = threadIdx.x;
    const int wv = tid >> 6, lane = tid & 63;
    const int l15 = lane & 15, kg8 = (lane >> 4) * 8;
    const int tt0 = (blockIdx.x * 2 + wv) * 16;
    const int bh = blockIdx.y, b = bh >> 2, h = bh & 3;
    u16* wl = &wls[wv][0][0];
    u16* wb = &wbs[wv][0][0];
    u16* bs = &bss[wv][0][0];

    // zero the pad regions PV will read: w_lds cols [144,160), wband [101,128)
    for (int i = lane; i < 16 * 8; i += 64) {
        const int t = i >> 3, c = 144 + ((i & 7) << 1);
        *reinterpret_cast<u32*>(&wl[t * WST + c]) = 0;
    }
    for (int i = lane; i < 16 * 27; i += 64) {
        const int t = i / 27, j = 101 + (i - t * 27);
        wb[t * WBST + j] = 0;
    }

    // ---- QK^T + emb logits ----
    const u16* qp = q + (size_t)(b * 1536 + tt0 + l15) * 256 + h * 64 + kg8;
    const bf16x8 a0 = ld8(qp);
    const bf16x8 a1 = ld8(qp + 32);
    const f32x4 zf = {0.f, 0.f, 0.f, 0.f};
    f32x4 dacc[9];
    f32x4 eacc[7];
    #pragma unroll
    for (int i = 0; i < 9; ++i) dacc[i] = zf;
    #pragma unroll
    for (int i = 0; i < 7; ++i) eacc[i] = zf;

    #pragma unroll
    for (int nf = 0; nf < 9; ++nf) {
        int s = tt0 - 64 + nf * 16 + l15;
        int sc = s < 0 ? 0 : (s > 1535 ? 1535 : s);
        const u16* kp = k + (size_t)(b * 1536 + sc) * 256 + h * 64 + kg8;
        dacc[nf] = MFMA16(a0, ld8(kp), dacc[nf], 0, 0, 0);
        dacc[nf] = MFMA16(a1, ld8(kp + 32), dacc[nf], 0, 0, 0);
    }
    #pragma unroll
    for (int jf = 0; jf < 7; ++jf) {
        const u16* ep = embR + (jf * 16 + l15) * 64 + kg8;
        eacc[jf] = MFMA16(a0, ld8(ep), eacc[jf], 0, 0, 0);
        eacc[jf] = MFMA16(a1, ld8(ep + 32), eacc[jf], 0, 0, 0);
    }
    // exchange band logits through LDS (D cols are j, need j = cs - t - 14)
    #pragma unroll
    for (int jf = 0; jf < 7; ++jf)
        #pragma unroll
        for (int r = 0; r < 4; ++r) {
            const int t = (lane >> 4) * 4 + r;
            bs[t * BST + jf * 16 + l15] = f2bf(eacc[jf][r]);
        }
    // combine + mask
    #pragma unroll
    for (int nf = 0; nf < 9; ++nf)
        #pragma unroll
        for (int r = 0; r < 4; ++r) {
            const int t = (lane >> 4) * 4 + r;
            const int cs = nf * 16 + l15;
            const int j = cs - t - 14;
            const int s = tt0 - 64 + cs;
            float v = dacc[nf][r];
            if (j >= 0 && j < 101 && s >= 0 && s < 1536)
                v += bf2f(bs[t * BST + j]);
            else
                v = -1e30f;
            dacc[nf][r] = v;
        }
    // ---- softmax (16-lane xor reduce per row) ----
    float inv[4];
    #pragma unroll
    for (int r = 0; r < 4; ++r) {
        float m = dacc[0][r];
        #pragma unroll
        for (int nf = 1; nf < 9; ++nf) m = fmaxf(m, dacc[nf][r]);
        m = fmaxf(m, __shfl_xor(m, 1));
        m = fmaxf(m, __shfl_xor(m, 2));
        m = fmaxf(m, __shfl_xor(m, 4));
        m = fmaxf(m, __shfl_xor(m, 8));
        float ss = 0.f;
        #pragma unroll
        for (int nf = 0; nf < 9; ++nf) {
            float e = __expf(dacc[nf][r] - m);
            dacc[nf][r] = e;
            ss += e;
        }
        ss += __shfl_xor(ss, 1);
        ss += __shfl_xor(ss, 2);
        ss += __shfl_xor(ss, 4);
        ss += __shfl_xor(ss, 8);
        inv[r] = 1.f / ss;
    }
    // write weights (band-window layout + band-shifted layout)
    #pragma unroll
    for (int nf = 0; nf < 9; ++nf)
        #pragma unroll
        for (int r = 0; r < 4; ++r) {
            const int t = (lane >> 4) * 4 + r;
            const int cs = nf * 16 + l15;
            const u16 w16 = f2bf(dacc[nf][r] * inv[r]);
            wl[t * WST + cs] = w16;
            const int j = cs - t - 14;
            if (j >= 0 && j < 101) wb[t * WBST + j] = w16;
        }

    // ---- PV + embPV (accumulate into same fragments) ----
    f32x4 oacc[4];
    #pragma unroll
    for (int i = 0; i < 4; ++i) oacc[i] = zf;
    #pragma unroll
    for (int kf = 0; kf < 5; ++kf) {
        const bf16x8 aw = ld8(&wl[l15 * WST + kf * 32 + kg8]);
        int sb = tt0 - 64 + kf * 32 + kg8;
        int sbc = sb < 0 ? 0 : (sb > 1528 ? 1528 : sb);  // clamped chunks have w==0
        #pragma unroll
        for (int nf = 0; nf < 4; ++nf) {
            const u16* cp = cont + (size_t)(b * 256 + h * 64 + nf * 16 + l15) * 1536 + sbc;
            oacc[nf] = MFMA16(aw, ld8(cp), oacc[nf], 0, 0, 0);
        }
    }
    #pragma unroll
    for (int kf = 0; kf < 4; ++kf) {
        const bf16x8 ab = ld8(&wb[l15 * WBST + kf * 32 + kg8]);
        #pragma unroll
        for (int nf = 0; nf < 4; ++nf) {
            const u16* ep = embT + (nf * 16 + l15) * 128 + kf * 32 + kg8;
            oacc[nf] = MFMA16(ab, ld8(ep), oacc[nf], 0, 0, 0);
        }
    }
    // store [b][l][ch] bf16
    #pragma unroll
    for (int nf = 0; nf < 4; ++nf)
        #pragma unroll
        for (int r = 0; r < 4; ++r) {
            const int t = (lane >> 4) * 4 + r;
            outp[(size_t)(b * 1536 + tt0 + t) * 256 + h * 64 + nf * 16 + l15] =
                f2bf(oacc[nf][r]);
        }
}

// ---------------------------------------------------------------------------
// BatchNorm(train) + ReLU + scale from bf16 preact [b][ch][l]
// ---------------------------------------------------------------------------
__global__ __launch_bounds__(256) void bn_apply(
    const u16* __restrict__ pre, const float* __restrict__ gamma,
    const float* __restrict__ beta, const float* __restrict__ scale,
    float* __restrict__ out)
{
    const int o = blockIdx.x;
    const int tid = threadIdx.x;
    float v[12];
    float sum = 0.f, sumsq = 0.f;
    #pragma unroll
    for (int i = 0; i < 12; ++i) {
        const int b = (i >= 6);
        const int l = (i - 6 * b) * 256 + tid;
        v[i] = bf2f(pre[(size_t)(b * 256 + o) * 1536 + l]);
        sum += v[i];
        sumsq = fmaf(v[i], v[i], sumsq);
    }
    #pragma unroll
    for (int off = 1; off < 64; off <<= 1) {
        sum += __shfl_xor(sum, off);
        sumsq += __shfl_xor(sumsq, off);
    }
    __shared__ float rs[4], rq[4];
    const int wave = tid >> 6;
    if ((tid & 63) == 0) { rs[wave] = sum; rq[wave] = sumsq; }
    __syncthreads();
    sum = rs[0] + rs[1] + rs[2] + rs[3];
    sumsq = rq[0] + rq[1] + rq[2] + rq[3];
    const float mean = sum * (1.f / 3072.f);
    const float var = sumsq * (1.f / 3072.f) - mean * mean;
    const float is = rsqrtf(var + 1e-5f);
    const float gm = gamma[o] * is;
    const float b2 = beta[o] - mean * gm;
    const float sc = scale[o];
    #pragma unroll
    for (int i = 0; i < 12; ++i) {
        const int b = (i >= 6);
        const int l = (i - 6 * b) * 256 + tid;
        out[(size_t)(b * 256 + o) * 1536 + l] = fmaxf(fmaf(v[i], gm, b2), 0.f) * sc;
    }
}

extern "C" void kernel_launch(void* const* d_in, const int* in_sizes, int n_in,
                              void* d_out, int out_size, void* d_ws, size_t ws_size,
                              hipStream_t stream) {
    const float* x     = (const float*)d_in[0];
    const float* Wc    = (const float*)d_in[1];
    const float* bc    = (const float*)d_in[2];
    const float* Wq    = (const float*)d_in[3];
    const float* bq    = (const float*)d_in[4];
    const float* Wk    = (const float*)d_in[5];
    const float* bk    = (const float*)d_in[6];
    const float* emb   = (const float*)d_in[7];
    const float* Wf    = (const float*)d_in[8];
    const float* bf    = (const float*)d_in[9];
    const float* gamma = (const float*)d_in[10];
    const float* beta  = (const float*)d_in[11];
    const float* scale = (const float*)d_in[12];
    float* out = (float*)d_out;
    u16* ws = (u16*)d_ws;

    const size_t NLC = 786432;  // B*C*L
    u16* xT   = ws;                 // [2][1536][256]
    u16* qb   = ws + NLC;           // [2][1536][256]
    u16* kb   = ws + 2 * NLC;       // [2][1536][256]
    u16* cbuf = ws + 3 * NLC;       // [2][256][1536]
    u16* abuf = ws + 4 * NLC;       // [2][1536][256]
    u16* pbuf = ws + 5 * NLC;       // [2][256][1536]
    u16* wcb  = ws + 6 * NLC;       // [256][256]
    u16* wqb  = wcb + 65536;
    u16* wkb  = wqb + 65536;
    u16* wfb  = wkb + 65536;
    u16* embR = wfb + 65536;        // [112][64]
    u16* embT = embR + 112 * 64;    // [64][128]

    prep_x<<<dim3(24, 4, 2), 256, 0, stream>>>(x, xT);
    prep_we<<<256, 256, 0, stream>>>(Wc, Wq, Wk, Wf, emb, wcb, wqb, wkb, wfb, embR, embT);
    gemm_qk<<<dim3(24, 4, 4), 256, 0, stream>>>(xT, wqb, bq, wkb, bk, qb, kb);
    gemm_cf<<<dim3(24, 4, 2), 256, 0, stream>>>(wcb, bc, xT, cbuf);
    attn_mfma<<<dim3(48, 8), 128, 0, stream>>>(qb, kb, cbuf, embR, embT, abuf);
    gemm_cf<<<dim3(24, 4, 2), 256, 0, stream>>>(wfb, bf, abuf, pbuf);
    bn_apply<<<256, 256, 0, stream>>>(pbuf, gamma, beta, scale, out);
}

// Round 8
// 117.869 us; speedup vs baseline: 4.0150x; 1.0576x over previous
//
#include <hip/hip_runtime.h>

typedef unsigned short u16;
typedef unsigned int u32;
typedef __bf16 bf16x8 __attribute__((ext_vector_type(8)));
typedef float f32x4 __attribute__((ext_vector_type(4)));

#define MFMA16 __builtin_amdgcn_mfma_f32_16x16x32_bf16

__device__ __forceinline__ u16 f2bf(float f) {
    u32 u = __float_as_uint(f);
    u32 r = (u + 0x7fffu + ((u >> 16) & 1u)) >> 16;
    return (u16)r;
}
__device__ __forceinline__ float bf2f(u16 h) {
    return __uint_as_float(((u32)h) << 16);
}
__device__ __forceinline__ bf16x8 ld8(const u16* p) {
    return *reinterpret_cast<const bf16x8*>(p);
}

// ---------------------------------------------------------------------------
// prep: z<2 -> transpose x slice b=z to xT [b][l][c] bf16 (as before);
//       z==2 -> convert W's + build emb tables. grid (24,4,3), 256 thr.
// ---------------------------------------------------------------------------
__global__ __launch_bounds__(256) void prep(
    const float* __restrict__ x,
    const float* __restrict__ Wc, const float* __restrict__ Wq,
    const float* __restrict__ Wk, const float* __restrict__ Wf,
    const float* __restrict__ emb,
    u16* __restrict__ xT,
    u16* __restrict__ wcb, u16* __restrict__ wqb, u16* __restrict__ wkb,
    u16* __restrict__ wfb, u16* __restrict__ embR, u16* __restrict__ embT)
{
    const int tid = threadIdx.x;
    const int z = blockIdx.z;
    if (z < 2) {
        __shared__ u16 tile[64][65];
        const int b = z, c0 = blockIdx.y * 64, l0 = blockIdx.x * 64;
        const int cc = tid >> 2, lq = (tid & 3) * 16;
        const float* xp = x + (size_t)((b * 256 + c0 + cc) * 1536 + l0 + lq);
        #pragma unroll
        for (int i = 0; i < 4; ++i) {
            float4 v = *reinterpret_cast<const float4*>(xp + i * 4);
            tile[cc][lq + i * 4 + 0] = f2bf(v.x);
            tile[cc][lq + i * 4 + 1] = f2bf(v.y);
            tile[cc][lq + i * 4 + 2] = f2bf(v.z);
            tile[cc][lq + i * 4 + 3] = f2bf(v.w);
        }
        __syncthreads();
        const int ll = tid >> 2, cq = (tid & 3) * 16;
        u16* op = xT + (size_t)((b * 1536 + l0 + ll) * 256 + c0 + cq);
        #pragma unroll
        for (int i = 0; i < 16; ++i) op[i] = tile[cq + i][ll];
    } else {
        const int idx0 = (blockIdx.y * 24 + blockIdx.x) * 256 + tid;
        for (int i = idx0; i < 65536; i += 24576) {
            wcb[i] = f2bf(Wc[i]); wqb[i] = f2bf(Wq[i]);
            wkb[i] = f2bf(Wk[i]); wfb[i] = f2bf(Wf[i]);
        }
        if (idx0 < 112 * 64) {
            const int j = idx0 >> 6, d = idx0 & 63;
            embR[idx0] = (j < 101) ? f2bf(0.3f * emb[(100 - j) * 64 + d]) : (u16)0;
        }
        if (idx0 < 64 * 128) {
            const int d = idx0 >> 7, j = idx0 & 127;
            embT[idx0] = (j < 101) ? f2bf(0.3f * emb[(100 - j) * 64 + d]) : (u16)0;
        }
    }
}

// ---------------------------------------------------------------------------
// gemm_qkc: fused q/k/content conv1x1, bf16 MFMA, no LDS (L2-resident).
// grid (24, 8, 6), 128 thr = 2 waves; z = which*2 + b, which: 0=q 1=k 2=content
// which<2:  out[b][l][ch]  (A = xT l-rows, B = W ch-rows)
// which==2: out[b][ch][l]  (A = W ch-rows, B = xT l-rows)   [same as r7 gemm_cf]
// Per-wave 32x32 tile, identical MFMA chain to round 7 -> bit-identical output.
// ---------------------------------------------------------------------------
__global__ __launch_bounds__(128) void gemm_qkc(
    const u16* __restrict__ xT,
    const u16* __restrict__ Wq, const float* __restrict__ bq,
    const u16* __restrict__ Wk, const float* __restrict__ bk,
    const u16* __restrict__ Wc, const float* __restrict__ bc,
    u16* __restrict__ qo, u16* __restrict__ ko, u16* __restrict__ co)
{
    const int tid = threadIdx.x, wv = tid >> 6, lane = tid & 63;
    const int l15 = lane & 15, kg8 = (lane >> 4) * 8;
    const int z = blockIdx.z, b = z & 1, which = z >> 1;
    const u16* W = (which == 0) ? Wq : (which == 1) ? Wk : Wc;
    const float* bias = (which == 0) ? bq : (which == 1) ? bk : bc;
    const int l0 = blockIdx.x * 64 + wv * 32;
    const int ch0 = blockIdx.y * 32;
    const u16* xp = xT + (size_t)(b * 1536 + l0 + l15) * 256 + kg8;
    const u16* wp = W + (size_t)(ch0 + l15) * 256 + kg8;
    const u16* ap = (which == 2) ? wp : xp;   // A operand rows
    const u16* bp = (which == 2) ? xp : wp;   // B operand rows
    const f32x4 zf = {0.f, 0.f, 0.f, 0.f};
    f32x4 acc[2][2] = {{zf, zf}, {zf, zf}};
    #pragma unroll
    for (int kd = 0; kd < 8; ++kd) {
        bf16x8 a0 = ld8(ap + kd * 32);
        bf16x8 a1 = ld8(ap + 4096 + kd * 32);
        bf16x8 b0 = ld8(bp + kd * 32);
        bf16x8 b1 = ld8(bp + 4096 + kd * 32);
        acc[0][0] = MFMA16(a0, b0, acc[0][0], 0, 0, 0);
        acc[0][1] = MFMA16(a0, b1, acc[0][1], 0, 0, 0);
        acc[1][0] = MFMA16(a1, b0, acc[1][0], 0, 0, 0);
        acc[1][1] = MFMA16(a1, b1, acc[1][1], 0, 0, 0);
    }
    if (which < 2) {
        u16* outp = which ? ko : qo;
        float bv[2];
        bv[0] = bias[ch0 + l15];
        bv[1] = bias[ch0 + 16 + l15];
        #pragma unroll
        for (int mf = 0; mf < 2; ++mf)
            #pragma unroll
            for (int nf = 0; nf < 2; ++nf)
                #pragma unroll
                for (int r = 0; r < 4; ++r) {
                    const int row = l0 + mf * 16 + (lane >> 4) * 4 + r;
                    outp[(size_t)(b * 1536 + row) * 256 + ch0 + nf * 16 + l15] =
                        f2bf(acc[mf][nf][r] + bv[nf]);
                }
    } else {
        #pragma unroll
        for (int mf = 0; mf < 2; ++mf)
            #pragma unroll
            for (int r = 0; r < 4; ++r) {
                const int ch = ch0 + mf * 16 + (lane >> 4) * 4 + r;
                const float bv = bias[ch];
                #pragma unroll
                for (int nf = 0; nf < 2; ++nf)
                    co[(size_t)(b * 256 + ch) * 1536 + l0 + nf * 16 + l15] =
                        f2bf(acc[mf][nf][r] + bv);
            }
    }
}

// ---------------------------------------------------------------------------
// gemm_f: final conv1x1 (content-layout path), bf16 MFMA. grid (24,8,2), 128 thr
// ---------------------------------------------------------------------------
__global__ __launch_bounds__(128) void gemm_f(
    const u16* __restrict__ W, const float* __restrict__ bias,
    const u16* __restrict__ srcT, u16* __restrict__ outp)
{
    const int tid = threadIdx.x, wv = tid >> 6, lane = tid & 63;
    const int l15 = lane & 15, kg8 = (lane >> 4) * 8;
    const int b = blockIdx.z;
    const int l0 = blockIdx.x * 64 + wv * 32;
    const int ch0 = blockIdx.y * 32;
    const u16* ap = W + (size_t)(ch0 + l15) * 256 + kg8;
    const u16* bp = srcT + (size_t)(b * 1536 + l0 + l15) * 256 + kg8;
    const f32x4 zf = {0.f, 0.f, 0.f, 0.f};
    f32x4 acc[2][2] = {{zf, zf}, {zf, zf}};
    #pragma unroll
    for (int kd = 0; kd < 8; ++kd) {
        bf16x8 a0 = ld8(ap + kd * 32);
        bf16x8 a1 = ld8(ap + 4096 + kd * 32);
        bf16x8 b0 = ld8(bp + kd * 32);
        bf16x8 b1 = ld8(bp + 4096 + kd * 32);
        acc[0][0] = MFMA16(a0, b0, acc[0][0], 0, 0, 0);
        acc[0][1] = MFMA16(a0, b1, acc[0][1], 0, 0, 0);
        acc[1][0] = MFMA16(a1, b0, acc[1][0], 0, 0, 0);
        acc[1][1] = MFMA16(a1, b1, acc[1][1], 0, 0, 0);
    }
    #pragma unroll
    for (int mf = 0; mf < 2; ++mf)
        #pragma unroll
        for (int r = 0; r < 4; ++r) {
            const int ch = ch0 + mf * 16 + (lane >> 4) * 4 + r;
            const float bv = bias[ch];
            #pragma unroll
            for (int nf = 0; nf < 2; ++nf)
                outp[(size_t)(b * 256 + ch) * 1536 + l0 + nf * 16 + l15] =
                    f2bf(acc[mf][nf][r] + bv);
        }
}

// ---------------------------------------------------------------------------
// attn_mfma: unchanged from round 7 (verified passing).
// ---------------------------------------------------------------------------
#define WST 168
#define WBST 136
#define BST 114

__global__ __launch_bounds__(128) void attn_mfma(
    const u16* __restrict__ q, const u16* __restrict__ k,
    const u16* __restrict__ cont, const u16* __restrict__ embR,
    const u16* __restrict__ embT, u16* __restrict__ outp)
{
    __shared__ u16 wls[2][16][WST];
    __shared__ u16 wbs[2][16][WBST];
    __shared__ u16 bss[2][16][BST];
    const int tid = threadIdx.x;
    const int wv = tid >> 6, lane = tid & 63;
    const int l15 = lane & 15, kg8 = (lane >> 4) * 8;
    const int tt0 = (blockIdx.x * 2 + wv) * 16;
    const int bh = blockIdx.y, b = bh >> 2, h = bh & 3;
    u16* wl = &wls[wv][0][0];
    u16* wb = &wbs[wv][0][0];
    u16* bs = &bss[wv][0][0];

    for (int i = lane; i < 16 * 8; i += 64) {
        const int t = i >> 3, c = 144 + ((i & 7) << 1);
        *reinterpret_cast<u32*>(&wl[t * WST + c]) = 0;
    }
    for (int i = lane; i < 16 * 27; i += 64) {
        const int t = i / 27, j = 101 + (i - t * 27);
        wb[t * WBST + j] = 0;
    }

    const u16* qp = q + (size_t)(b * 1536 + tt0 + l15) * 256 + h * 64 + kg8;
    const bf16x8 a0 = ld8(qp);
    const bf16x8 a1 = ld8(qp + 32);
    const f32x4 zf = {0.f, 0.f, 0.f, 0.f};
    f32x4 dacc[9];
    f32x4 eacc[7];
    #pragma unroll
    for (int i = 0; i < 9; ++i) dacc[i] = zf;
    #pragma unroll
    for (int i = 0; i < 7; ++i) eacc[i] = zf;

    #pragma unroll
    for (int nf = 0; nf < 9; ++nf) {
        int s = tt0 - 64 + nf * 16 + l15;
        int sc = s < 0 ? 0 : (s > 1535 ? 1535 : s);
        const u16* kp = k + (size_t)(b * 1536 + sc) * 256 + h * 64 + kg8;
        dacc[nf] = MFMA16(a0, ld8(kp), dacc[nf], 0, 0, 0);
        dacc[nf] = MFMA16(a1, ld8(kp + 32), dacc[nf], 0, 0, 0);
    }
    #pragma unroll
    for (int jf = 0; jf < 7; ++jf) {
        const u16* ep = embR + (jf * 16 + l15) * 64 + kg8;
        eacc[jf] = MFMA16(a0, ld8(ep), eacc[jf], 0, 0, 0);
        eacc[jf] = MFMA16(a1, ld8(ep + 32), eacc[jf], 0, 0, 0);
    }
    #pragma unroll
    for (int jf = 0; jf < 7; ++jf)
        #pragma unroll
        for (int r = 0; r < 4; ++r) {
            const int t = (lane >> 4) * 4 + r;
            bs[t * BST + jf * 16 + l15] = f2bf(eacc[jf][r]);
        }
    #pragma unroll
    for (int nf = 0; nf < 9; ++nf)
        #pragma unroll
        for (int r = 0; r < 4; ++r) {
            const int t = (lane >> 4) * 4 + r;
            const int cs = nf * 16 + l15;
            const int j = cs - t - 14;
            const int s = tt0 - 64 + cs;
            float v = dacc[nf][r];
            if (j >= 0 && j < 101 && s >= 0 && s < 1536)
                v += bf2f(bs[t * BST + j]);
            else
                v = -1e30f;
            dacc[nf][r] = v;
        }
    float inv[4];
    #pragma unroll
    for (int r = 0; r < 4; ++r) {
        float m = dacc[0][r];
        #pragma unroll
        for (int nf = 1; nf < 9; ++nf) m = fmaxf(m, dacc[nf][r]);
        m = fmaxf(m, __shfl_xor(m, 1));
        m = fmaxf(m, __shfl_xor(m, 2));
        m = fmaxf(m, __shfl_xor(m, 4));
        m = fmaxf(m, __shfl_xor(m, 8));
        float ss = 0.f;
        #pragma unroll
        for (int nf = 0; nf < 9; ++nf) {
            float e = __expf(dacc[nf][r] - m);
            dacc[nf][r] = e;
            ss += e;
        }
        ss += __shfl_xor(ss, 1);
        ss += __shfl_xor(ss, 2);
        ss += __shfl_xor(ss, 4);
        ss += __shfl_xor(ss, 8);
        inv[r] = 1.f / ss;
    }
    #pragma unroll
    for (int nf = 0; nf < 9; ++nf)
        #pragma unroll
        for (int r = 0; r < 4; ++r) {
            const int t = (lane >> 4) * 4 + r;
            const int cs = nf * 16 + l15;
            const u16 w16 = f2bf(dacc[nf][r] * inv[r]);
            wl[t * WST + cs] = w16;
            const int j = cs - t - 14;
            if (j >= 0 && j < 101) wb[t * WBST + j] = w16;
        }

    f32x4 oacc[4];
    #pragma unroll
    for (int i = 0; i < 4; ++i) oacc[i] = zf;
    #pragma unroll
    for (int kf = 0; kf < 5; ++kf) {
        const bf16x8 aw = ld8(&wl[l15 * WST + kf * 32 + kg8]);
        int sb = tt0 - 64 + kf * 32 + kg8;
        int sbc = sb < 0 ? 0 : (sb > 1528 ? 1528 : sb);
        #pragma unroll
        for (int nf = 0; nf < 4; ++nf) {
            const u16* cp = cont + (size_t)(b * 256 + h * 64 + nf * 16 + l15) * 1536 + sbc;
            oacc[nf] = MFMA16(aw, ld8(cp), oacc[nf], 0, 0, 0);
        }
    }
    #pragma unroll
    for (int kf = 0; kf < 4; ++kf) {
        const bf16x8 ab = ld8(&wb[l15 * WBST + kf * 32 + kg8]);
        #pragma unroll
        for (int nf = 0; nf < 4; ++nf) {
            const u16* ep = embT + (nf * 16 + l15) * 128 + kf * 32 + kg8;
            oacc[nf] = MFMA16(ab, ld8(ep), oacc[nf], 0, 0, 0);
        }
    }
    #pragma unroll
    for (int nf = 0; nf < 4; ++nf)
        #pragma unroll
        for (int r = 0; r < 4; ++r) {
            const int t = (lane >> 4) * 4 + r;
            outp[(size_t)(b * 1536 + tt0 + t) * 256 + h * 64 + nf * 16 + l15] =
                f2bf(oacc[nf][r]);
        }
}

// ---------------------------------------------------------------------------
// BatchNorm(train) + ReLU + scale from bf16 preact [b][ch][l]  (unchanged)
// ---------------------------------------------------------------------------
__global__ __launch_bounds__(256) void bn_apply(
    const u16* __restrict__ pre, const float* __restrict__ gamma,
    const float* __restrict__ beta, const float* __restrict__ scale,
    float* __restrict__ out)
{
    const int o = blockIdx.x;
    const int tid = threadIdx.x;
    float v[12];
    float sum = 0.f, sumsq = 0.f;
    #pragma unroll
    for (int i = 0; i < 12; ++i) {
        const int b = (i >= 6);
        const int l = (i - 6 * b) * 256 + tid;
        v[i] = bf2f(pre[(size_t)(b * 256 + o) * 1536 + l]);
        sum += v[i];
        sumsq = fmaf(v[i], v[i], sumsq);
    }
    #pragma unroll
    for (int off = 1; off < 64; off <<= 1) {
        sum += __shfl_xor(sum, off);
        sumsq += __shfl_xor(sumsq, off);
    }
    __shared__ float rs[4], rq[4];
    const int wave = tid >> 6;
    if ((tid & 63) == 0) { rs[wave] = sum; rq[wave] = sumsq; }
    __syncthreads();
    sum = rs[0] + rs[1] + rs[2] + rs[3];
    sumsq = rq[0] + rq[1] + rq[2] + rq[3];
    const float mean = sum * (1.f / 3072.f);
    const float var = sumsq * (1.f / 3072.f) - mean * mean;
    const float is = rsqrtf(var + 1e-5f);
    const float gm = gamma[o] * is;
    const float b2 = beta[o] - mean * gm;
    const float sc = scale[o];
    #pragma unroll
    for (int i = 0; i < 12; ++i) {
        const int b = (i >= 6);
        const int l = (i - 6 * b) * 256 + tid;
        out[(size_t)(b * 256 + o) * 1536 + l] = fmaxf(fmaf(v[i], gm, b2), 0.f) * sc;
    }
}

extern "C" void kernel_launch(void* const* d_in, const int* in_sizes, int n_in,
                              void* d_out, int out_size, void* d_ws, size_t ws_size,
                              hipStream_t stream) {
    const float* x     = (const float*)d_in[0];
    const float* Wc    = (const float*)d_in[1];
    const float* bc    = (const float*)d_in[2];
    const float* Wq    = (const float*)d_in[3];
    const float* bq    = (const float*)d_in[4];
    const float* Wk    = (const float*)d_in[5];
    const float* bk    = (const float*)d_in[6];
    const float* emb   = (const float*)d_in[7];
    const float* Wf    = (const float*)d_in[8];
    const float* bf    = (const float*)d_in[9];
    const float* gamma = (const float*)d_in[10];
    const float* beta  = (const float*)d_in[11];
    const float* scale = (const float*)d_in[12];
    float* out = (float*)d_out;
    u16* ws = (u16*)d_ws;

    const size_t NLC = 786432;  // B*C*L
    u16* xT   = ws;                 // [2][1536][256]
    u16* qb   = ws + NLC;           // [2][1536][256]
    u16* kb   = ws + 2 * NLC;       // [2][1536][256]
    u16* cbuf = ws + 3 * NLC;       // [2][256][1536]
    u16* abuf = ws + 4 * NLC;       // [2][1536][256]
    u16* pbuf = ws + 5 * NLC;       // [2][256][1536]
    u16* wcb  = ws + 6 * NLC;       // [256][256]
    u16* wqb  = wcb + 65536;
    u16* wkb  = wqb + 65536;
    u16* wfb  = wkb + 65536;
    u16* embR = wfb + 65536;        // [112][64]
    u16* embT = embR + 112 * 64;    // [64][128]

    prep<<<dim3(24, 4, 3), 256, 0, stream>>>(x, Wc, Wq, Wk, Wf, emb,
                                             xT, wcb, wqb, wkb, wfb, embR, embT);
    gemm_qkc<<<dim3(24, 8, 6), 128, 0, stream>>>(xT, wqb, bq, wkb, bk, wcb, bc,
                                                 qb, kb, cbuf);
    attn_mfma<<<dim3(48, 8), 128, 0, stream>>>(qb, kb, cbuf, embR, embT, abuf);
    gemm_f<<<dim3(24, 8, 2), 128, 0, stream>>>(wfb, bf, abuf, pbuf);
    bn_apply<<<256, 256, 0, stream>>>(pbuf, gamma, beta, scale, out);
}